// Round 4
// baseline (325.337 us; speedup 1.0000x reference)
//
#include <hip/hip_runtime.h>

#define NK 256   // IN == OUT == 256

typedef __attribute__((ext_vector_type(8))) short bf16x8;
typedef __attribute__((ext_vector_type(4))) float f32x4;

union BF8 { bf16x8 v; ushort u[8]; uint4 q; };

__device__ inline ushort f2bf(float f) {
    // round-to-nearest-even fp32 -> bf16 (inputs are finite normals)
    uint u = __float_as_uint(f);
    u += 0x7FFFu + ((u >> 16) & 1u);
    return (ushort)(u >> 16);
}

// ---- pre-kernel: binarize W once -> workspace as bf16 {0, 1.0} --------------
// 256x256 fp32 -> 128 KB ushort. Runs once; W stays L2/L3-hot for the main
// kernel. Removes all per-block binarize VALU + LDS staging + barriers.
__global__ void binarize_w(const float* __restrict__ w, ushort* __restrict__ wb)
{
    int i = blockIdx.x * 256 + threadIdx.x;        // 8192 threads x 8 elems
    const float4* wp = (const float4*)(w + (size_t)i * 8);
    float4 w0 = wp[0], w1 = wp[1];
    uint4 pk;
    pk.x = (w0.x > 0.8f ? 0x00003F80u : 0u) | (w0.y > 0.8f ? 0x3F800000u : 0u);
    pk.y = (w0.z > 0.8f ? 0x00003F80u : 0u) | (w0.w > 0.8f ? 0x3F800000u : 0u);
    pk.z = (w1.x > 0.8f ? 0x00003F80u : 0u) | (w1.y > 0.8f ? 0x3F800000u : 0u);
    pk.w = (w1.z > 0.8f ? 0x00003F80u : 0u) | (w1.w > 0.8f ? 0x3F800000u : 0u);
    *(uint4*)(wb + (size_t)i * 8) = pk;
}

// ---- main kernel: barrier-free, LDS-free -----------------------------------
// 8 waves/block, wave wv owns rows [blk*128 + wv*16, +16). Waves are fully
// independent (no __syncthreads anywhere) so co-resident waves de-phase and
// keep HBM busy during each other's compute phases (rounds 0/3 were stuck at
// 37% HBM duty with lockstepped phase programs).
// B fragments load directly from the 128 KB w_bin: every wave on the chip
// reads the identical address sequence -> L1-resident s-slices (s,s+1 share
// 128B lines; 32 KB working set per s-pair == L1 size).
__global__ __launch_bounds__(512, 2) void fused_binlinear(
    const float* __restrict__ x, const ushort* __restrict__ wb, float* __restrict__ out)
{
    const int tid = threadIdx.x;
    const int wv  = tid >> 6;
    const int ln  = tid & 63;
    const int m   = ln & 15;   // MFMA m / n / col lane index
    const int q   = ln >> 4;   // MFMA k-quad / row-quad

    const int row0 = blockIdx.x * 128 + wv * 16;

    // ---- A loads: 16 rows x 256 k fp32, all issued upfront (deep HBM queue) ----
    const float4* xv = (const float4*)(x + (size_t)(row0 + m) * NK + q * 8);
    float4 a0[8], a1[8];
#pragma unroll
    for (int s = 0; s < 8; ++s) { a0[s] = xv[s * 8]; a1[s] = xv[s * 8 + 1]; }

    // ---- convert A to bf16 fragments: lane holds A[m][k = s*32 + q*8 + j] ----
    bf16x8 fa[8];
#pragma unroll
    for (int s = 0; s < 8; ++s) {
        BF8 t;
        t.u[0] = f2bf(a0[s].x); t.u[1] = f2bf(a0[s].y);
        t.u[2] = f2bf(a0[s].z); t.u[3] = f2bf(a0[s].w);
        t.u[4] = f2bf(a1[s].x); t.u[5] = f2bf(a1[s].y);
        t.u[6] = f2bf(a1[s].z); t.u[7] = f2bf(a1[s].w);
        fa[s] = t.v;
    }

    // ---- MFMA: B frag for (s,t) = wb[row = t*16+m][k = s*32 + q*8 .. +8] ----
    // lane-invariant base: wl = wb + m*NK + q*8; offsets are compile-time.
    const ushort* wl = wb + m * NK + q * 8;

    f32x4 acc[16];
#pragma unroll
    for (int t = 0; t < 16; ++t) acc[t] = (f32x4){0.f, 0.f, 0.f, 0.f};
#pragma unroll
    for (int s = 0; s < 8; ++s) {
#pragma unroll
        for (int t = 0; t < 16; ++t) {
            bf16x8 fb = *(const bf16x8*)(wl + t * 16 * NK + s * 32);
            acc[t] = __builtin_amdgcn_mfma_f32_16x16x32_bf16(fa[s], fb, acc[t], 0, 0, 0);
        }
    }

    // ---- fused row-mean: wave holds full rows; C/D layout col=m, row=q*4+r ----
    float rs[4];
#pragma unroll
    for (int r = 0; r < 4; ++r) {
        float s = 0.f;
#pragma unroll
        for (int t = 0; t < 16; ++t) s += acc[t][r];
        rs[r] = s;
    }
#pragma unroll
    for (int r = 0; r < 4; ++r) {
        rs[r] += __shfl_xor(rs[r], 1, 64);
        rs[r] += __shfl_xor(rs[r], 2, 64);
        rs[r] += __shfl_xor(rs[r], 4, 64);
        rs[r] += __shfl_xor(rs[r], 8, 64);
        rs[r] *= (1.0f / 256.0f);
    }

    // ---- store: plain dword stores in a tight per-wave burst (L2 coalesces;
    //      each 128B out-line is written entirely by one wave's burst) ----
#pragma unroll
    for (int t = 0; t < 16; ++t) {
#pragma unroll
        for (int r = 0; r < 4; ++r) {
            out[(size_t)(row0 + q * 4 + r) * NK + t * 16 + m] = acc[t][r] - rs[r];
        }
    }
}

extern "C" void kernel_launch(void* const* d_in, const int* in_sizes, int n_in,
                              void* d_out, int out_size, void* d_ws, size_t ws_size,
                              hipStream_t stream) {
    const float* x  = (const float*)d_in[0];   // [131072, 256] fp32
    const float* w  = (const float*)d_in[1];   // [256, 256] fp32
    float* out      = (float*)d_out;           // [131072, 256] fp32
    ushort* wbin    = (ushort*)d_ws;           // 128 KB bf16 binarized W
    const int M     = in_sizes[0] / NK;        // 131072

    binarize_w<<<32, 256, 0, stream>>>(w, wbin);           // 65536 elems / 8
    fused_binlinear<<<M / 128, 512, 0, stream>>>(x, wbin, out);
}

// Round 5
// 242.613 us; speedup vs baseline: 1.3410x; 1.3410x over previous
//
#include <hip/hip_runtime.h>

#define NK  256   // IN == OUT == 256
#define LDN 264   // LDS row stride in ushort (528B -> 2-way bank aliasing, free per m136)

typedef __attribute__((ext_vector_type(8))) short bf16x8;
typedef __attribute__((ext_vector_type(4))) float f32x4;

union BF8 { bf16x8 v; ushort u[8]; uint4 q; };

__device__ inline ushort f2bf(float f) {
    // round-to-nearest-even fp32 -> bf16 (inputs are finite normals)
    uint u = __float_as_uint(f);
    u += 0x7FFFu + ((u >> 16) & 1u);
    return (ushort)(u >> 16);
}

// ---- pre-kernel: binarize W once -> workspace as bf16 {0, 1.0} --------------
// 256x256 fp32 -> 128 KB ushort. Makes main-kernel B staging a pure copy
// (half the global W bytes, zero binarize VALU in the hot kernel).
__global__ void binarize_w(const float* __restrict__ w, ushort* __restrict__ wb)
{
    int i = blockIdx.x * 256 + threadIdx.x;        // 8192 threads x 8 elems
    const float4* wp = (const float4*)(w + (size_t)i * 8);
    float4 w0 = wp[0], w1 = wp[1];
    uint4 pk;
    pk.x = (w0.x > 0.8f ? 0x00003F80u : 0u) | (w0.y > 0.8f ? 0x3F800000u : 0u);
    pk.y = (w0.z > 0.8f ? 0x00003F80u : 0u) | (w0.w > 0.8f ? 0x3F800000u : 0u);
    pk.z = (w1.x > 0.8f ? 0x00003F80u : 0u) | (w1.y > 0.8f ? 0x3F800000u : 0u);
    pk.w = (w1.z > 0.8f ? 0x00003F80u : 0u) | (w1.w > 0.8f ? 0x3F800000u : 0u);
    *(uint4*)(wb + (size_t)i * 8) = pk;
}

// ---- main kernel: 2 M-tiles per block over a fully-resident 132 KB B --------
// Phase-duty fix: tile 1 has NO staging and NO barriers (B stays in LDS), and
// its x-loads are issued during tile 0's MFMA -> tile-0 store drain and tile-1
// x-loads/compute overlap. Store bursts are sched_barrier-fenced so the
// compiler can't scatter them (rounds 1/2: scattered bursts -> L2 dirty-window
// overflow -> partial-line RMW, +700 MB HBM traffic).
__global__ __launch_bounds__(512, 2) void fused_binlinear(
    const float* __restrict__ x, const ushort* __restrict__ wb, float* __restrict__ out)
{
    __shared__ ushort Bs[256 * LDN];   // 132 KB -> 1 block/CU

    const int tid = threadIdx.x;
    const int wv  = tid >> 6;
    const int ln  = tid & 63;
    const int m   = ln & 15;   // MFMA m / n / col lane index
    const int q   = ln >> 4;   // MFMA k-quad / row-quad

    // block covers rows [blk*256, +256): tile0 = first 128, tile1 = second 128
    const size_t rowBase = (size_t)blockIdx.x * 256 + wv * 16;

    // ---- A0 loads issued first: 16 rows x 256 k fp32, fly during B staging ----
    const float4* xv0 = (const float4*)(x + (rowBase + m) * NK + q * 8);
    float4 a0[8], a1[8];
#pragma unroll
    for (int s = 0; s < 8; ++s) { a0[s] = xv0[s * 8]; a1[s] = xv0[s * 8 + 1]; }

    // ---- stage full binarized B (128 KB bf16, pure copy, 264-pad rows) ----
#pragma unroll
    for (int i = 0; i < 16; ++i) {
        int cc = i * 512 + tid;          // 8-elem chunk id, 8192 total
        int n  = cc >> 5;                // 0..255
        int kc = cc & 31;
        *(uint4*)(&Bs[n * LDN + kc * 8]) =
            *(const uint4*)(wb + (size_t)n * NK + kc * 8);
    }
    __syncthreads();   // the ONLY barrier in the kernel

    // ---- convert A0: lane holds A[m][k = s*32 + q*8 + j] ----
    bf16x8 fa[8];
#pragma unroll
    for (int s = 0; s < 8; ++s) {
        BF8 t;
        t.u[0] = f2bf(a0[s].x); t.u[1] = f2bf(a0[s].y);
        t.u[2] = f2bf(a0[s].z); t.u[3] = f2bf(a0[s].w);
        t.u[4] = f2bf(a1[s].x); t.u[5] = f2bf(a1[s].y);
        t.u[6] = f2bf(a1[s].z); t.u[7] = f2bf(a1[s].w);
        fa[s] = t.v;
    }

    // ---- issue A1 loads now: they fly under tile-0 MFMA + store drain ----
    const float4* xv1 = (const float4*)(x + (rowBase + 128 + m) * NK + q * 8);
#pragma unroll
    for (int s = 0; s < 8; ++s) { a0[s] = xv1[s * 8]; a1[s] = xv1[s * 8 + 1]; }

    // ---- tile 0 MFMA: 8 k-steps x 16 n-tiles; B row t*16+m, k = s*32+q*8 ----
    f32x4 acc[16];
#pragma unroll
    for (int t = 0; t < 16; ++t) acc[t] = (f32x4){0.f, 0.f, 0.f, 0.f};
#pragma unroll
    for (int s = 0; s < 8; ++s) {
#pragma unroll
        for (int t = 0; t < 16; ++t) {
            bf16x8 fb = *(const bf16x8*)(&Bs[(t * 16 + m) * LDN + s * 32 + q * 8]);
            acc[t] = __builtin_amdgcn_mfma_f32_16x16x32_bf16(fa[s], fb, acc[t], 0, 0, 0);
        }
    }

    // ---- tile 0: fused row-mean (C/D layout col=m, row=q*4+r) + tight store ----
    float rs[4];
#pragma unroll
    for (int r = 0; r < 4; ++r) {
        float s = 0.f;
#pragma unroll
        for (int t = 0; t < 16; ++t) s += acc[t][r];
        rs[r] = s;
    }
#pragma unroll
    for (int r = 0; r < 4; ++r) {
        rs[r] += __shfl_xor(rs[r], 1, 64);
        rs[r] += __shfl_xor(rs[r], 2, 64);
        rs[r] += __shfl_xor(rs[r], 4, 64);
        rs[r] += __shfl_xor(rs[r], 8, 64);
        rs[r] *= (1.0f / 256.0f);
    }
    __builtin_amdgcn_sched_barrier(0);   // keep store burst contiguous
#pragma unroll
    for (int t = 0; t < 16; ++t) {
#pragma unroll
        for (int r = 0; r < 4; ++r) {
            out[(rowBase + q * 4 + r) * NK + t * 16 + m] = acc[t][r] - rs[r];
        }
    }
    __builtin_amdgcn_sched_barrier(0);   // stores issued; they drain under tile 1

    // ---- tile 1: convert A1 (loads landed during tile-0 compute) ----
#pragma unroll
    for (int s = 0; s < 8; ++s) {
        BF8 t;
        t.u[0] = f2bf(a0[s].x); t.u[1] = f2bf(a0[s].y);
        t.u[2] = f2bf(a0[s].z); t.u[3] = f2bf(a0[s].w);
        t.u[4] = f2bf(a1[s].x); t.u[5] = f2bf(a1[s].y);
        t.u[6] = f2bf(a1[s].z); t.u[7] = f2bf(a1[s].w);
        fa[s] = t.v;
    }

    // ---- tile 1 MFMA: B still resident in LDS, no staging, no barrier ----
#pragma unroll
    for (int t = 0; t < 16; ++t) acc[t] = (f32x4){0.f, 0.f, 0.f, 0.f};
#pragma unroll
    for (int s = 0; s < 8; ++s) {
#pragma unroll
        for (int t = 0; t < 16; ++t) {
            bf16x8 fb = *(const bf16x8*)(&Bs[(t * 16 + m) * LDN + s * 32 + q * 8]);
            acc[t] = __builtin_amdgcn_mfma_f32_16x16x32_bf16(fa[s], fb, acc[t], 0, 0, 0);
        }
    }

    // ---- tile 1: row-mean + tight store burst ----
#pragma unroll
    for (int r = 0; r < 4; ++r) {
        float s = 0.f;
#pragma unroll
        for (int t = 0; t < 16; ++t) s += acc[t][r];
        rs[r] = s;
    }
#pragma unroll
    for (int r = 0; r < 4; ++r) {
        rs[r] += __shfl_xor(rs[r], 1, 64);
        rs[r] += __shfl_xor(rs[r], 2, 64);
        rs[r] += __shfl_xor(rs[r], 4, 64);
        rs[r] += __shfl_xor(rs[r], 8, 64);
        rs[r] *= (1.0f / 256.0f);
    }
    __builtin_amdgcn_sched_barrier(0);
#pragma unroll
    for (int t = 0; t < 16; ++t) {
#pragma unroll
        for (int r = 0; r < 4; ++r) {
            out[(rowBase + 128 + q * 4 + r) * NK + t * 16 + m] = acc[t][r] - rs[r];
        }
    }
}

extern "C" void kernel_launch(void* const* d_in, const int* in_sizes, int n_in,
                              void* d_out, int out_size, void* d_ws, size_t ws_size,
                              hipStream_t stream) {
    const float* x  = (const float*)d_in[0];   // [131072, 256] fp32
    const float* w  = (const float*)d_in[1];   // [256, 256] fp32
    float* out      = (float*)d_out;           // [131072, 256] fp32
    ushort* wbin    = (ushort*)d_ws;           // 128 KB bf16 binarized W
    const int M     = in_sizes[0] / NK;        // 131072

    binarize_w<<<32, 256, 0, stream>>>(w, wbin);            // 65536 elems / 8
    fused_binlinear<<<M / 256, 512, 0, stream>>>(x, wbin, out);
}